// Round 7
// baseline (1224.804 us; speedup 1.0000x reference)
//
#include <hip/hip_runtime.h>
#include <math.h>

#define BT 2048

typedef __attribute__((ext_vector_type(8))) short bf16x8;
typedef __attribute__((ext_vector_type(4))) float f32x4;
typedef __attribute__((ext_vector_type(4))) unsigned short u16x4;

__device__ inline unsigned short f2bf(float f) {
    union { float f; unsigned u; } v; v.f = f;
    unsigned r = (v.u >> 16) & 1u;
    return (unsigned short)((v.u + 0x7FFFu + r) >> 16);
}
__device__ inline float bf2f(unsigned short s) {
    union { unsigned u; float f; } v; v.u = ((unsigned)s) << 16;
    return v.f;
}
__device__ inline float ubf(unsigned u) {
    union { unsigned u; float f; } v; v.u = u; return v.f;
}
// HW packed convert: lo16 = bf16(a), hi16 = bf16(b). Single VALU op.
__device__ inline unsigned cvt2(float a, float b) {
    unsigned r;
    asm("v_cvt_pk_bf16_f32 %0, %1, %2" : "=v"(r) : "v"(a), "v"(b));
    return r;
}

__device__ inline float dot4(const float4 a, const float4 b) {
    return fmaf(a.x, b.x, fmaf(a.y, b.y, fmaf(a.z, b.z, a.w * b.w)));
}

union F8 { float4 v2[2]; float f[8]; };

// x/feats LDS planes: [64 rows][264 cols] ushort (pad 8 cols kills stride-256 conflicts)
#define XP 264

// ---------------------------------------------------------------------------
// Pre-swizzle weights into MFMA B-fragment order, SPLIT bf16 hi/lo. (GNN only)
__global__ __launch_bounds__(256) void k_prep(const float* __restrict__ inW,
                                              const float* __restrict__ gatW,
                                              unsigned short* __restrict__ dst) {
    int gid = blockIdx.x * 256 + threadIdx.x;   // 0..65535
    int mat = gid >> 14;
    int r   = gid & 16383;
    int ks  = r >> 10;
    int nt  = (r >> 6) & 15;
    int lane = r & 63;
    int ln15 = lane & 15, q = lane >> 4;
    int n  = nt * 16 + ln15;
    int k0 = ks * 32 + q * 8;
    const float* src; bool tr;
    if (mat == 0) { src = inW; tr = true; }
    else          { src = gatW + (size_t)(mat - 1) * 65536; tr = false; }
    unsigned short* d = dst + ((size_t)mat * 16384 + r) * 16;
    if (ks < 8) {
        #pragma unroll
        for (int j = 0; j < 8; j++) {
            float v = tr ? src[n * 256 + k0 + j] : src[(size_t)(k0 + j) * 256 + n];
            unsigned short hi = f2bf(v);
            d[j]     = hi;
            d[8 + j] = f2bf(v - bf2f(hi));
        }
    } else {
        #pragma unroll
        for (int j = 0; j < 8; j++) { d[j] = 0; d[8 + j] = 0; }
    }
}

// ---------------------------------------------------------------------------
// Aux B-tiles: a_src = x @ (W . att_src) folded into the phase-B GEMM.
__global__ __launch_bounds__(64) void k_prep_aux(const float* __restrict__ gatW,
                                                 const float* __restrict__ attS,
                                                 const float* __restrict__ attD,
                                                 unsigned short* __restrict__ dst) {
    int l  = blockIdx.x >> 3;      // 0..2
    int ks = blockIdx.x & 7;       // 0..7
    int lane = threadIdx.x;
    int ln15 = lane & 15, q = lane >> 4;
    int k0 = ks * 32 + q * 8;
    const float* W = gatW + (size_t)l * 65536;
    unsigned short* d = dst + ((size_t)(l * 8 + ks) * 64 + lane) * 16;
    #pragma unroll
    for (int j = 0; j < 8; j++) {
        float v = 0.f;
        if (ln15 < 8) {
            int head = ln15 & 3;
            const float* a = (ln15 < 4 ? attS : attD) + (size_t)l * 256 + head * 64;
            const float* wr = W + (size_t)(k0 + j) * 256 + head * 64;
            for (int c = 0; c < 64; c++) v = fmaf(wr[c], a[c], v);
        }
        unsigned short hi = f2bf(v);
        d[j]     = hi;
        d[8 + j] = f2bf(v - bf2f(hi));
    }
}

// ---------------------------------------------------------------------------
// Fully fused GNN. Round-7 change: phase E register diet to eliminate the
// 1.9 GB scratch spill while keeping 2 blocks/CU (84% occ).
//  - two-pass softmax: pass 1 = max only (no lg[16] array), pass 2 recomputes
//    logits, exponentiates, accumulates sm, packs UNNORMALIZED alpha.
//  - normalization deferred through the linear PV MFMA: macc (residual+bias)
//    is pre-scaled by sm_row, MFMA accumulates e.H, post-scale by 1/sm_row.
//    (res*sm + P@H)/sm == res + msg, exact up to fp32 rounding.
__global__ __launch_bounds__(1024, 8) void k_gnn(const float* __restrict__ feats,
                                                 const float* __restrict__ boxes,
                                                 const float* __restrict__ maskp,
                                                 const unsigned short* __restrict__ BswAll,
                                                 const unsigned short* __restrict__ auxB,
                                                 const float* __restrict__ inb,
                                                 const float* __restrict__ edgeW,
                                                 const float* __restrict__ attEg,
                                                 const float* __restrict__ gbias,
                                                 const float* __restrict__ glns,
                                                 const float* __restrict__ glnb,
                                                 float* __restrict__ framebuf) {
    int bt = blockIdx.x;
    size_t fbase = (size_t)bt * 64 * 256;

    __shared__ __align__(16) unsigned short U[256 * 136]; // x planes OR hT (aliased)
    __shared__ float pxS[64], pyS[64], vmS[64];
    __shared__ float loopS[192];
    __shared__ float asrcS[4][64], adstS[4][64];  // PER-HEAD (from aux MFMA)
    __shared__ float wESall[36];                  // [l][e][h]
    __shared__ float sumsS[64][8];                // [d][head*2 + {sum,sum2}]
    __shared__ float mrsS[64][2];
    __shared__ float nvS;

    unsigned short* xH = U;                 // x hi plane [64][XP]
    unsigned short* xL = U + 64 * XP;       // x lo plane

    int tid = threadIdx.x, lane = tid & 63, w = tid >> 6;   // w 0..15
    int ln15 = lane & 15, q = lane >> 4;
    int nt = w;
    int eh = w >> 2;
    int dq = w & 3;

    if (tid < 64) {
        const float* bx = boxes + (size_t)(bt * 64 + tid) * 5;
        pxS[tid] = bx[1];
        pyS[tid] = bx[2];
        vmS[tid] = maskp[bt * 64 + tid];
    } else if (tid < 100) {
        int idx = tid - 64;
        int l = idx / 12, r2 = idx - l * 12;
        int e = r2 >> 2, h2 = r2 & 3;
        float sm = 0.f;
        const float* ew = edgeW + (size_t)l * 768 + e * 256 + h2 * 64;
        const float* ae = attEg + (size_t)l * 256 + h2 * 64;
        for (int c = 0; c < 64; c++) sm += ew[c] * ae[c];
        wESall[idx] = sm;
    }
    #pragma unroll
    for (int j = 0; j < 4; j++) {
        int g = j * 4096 + tid * 4;
        int row = g >> 8, col = g & 255;
        float4 v4 = *(const float4*)&feats[fbase + g];
        unsigned p0 = cvt2(v4.x, v4.y);
        unsigned p1 = cvt2(v4.z, v4.w);
        float h0 = ubf(p0 << 16), h1 = ubf(p0 & 0xFFFF0000u);
        float h2 = ubf(p1 << 16), h3 = ubf(p1 & 0xFFFF0000u);
        unsigned l0 = cvt2(v4.x - h0, v4.y - h1);
        unsigned l1 = cvt2(v4.z - h2, v4.w - h3);
        *(unsigned*)&xH[row * XP + col]     = p0;
        *(unsigned*)&xH[row * XP + col + 2] = p1;
        *(unsigned*)&xL[row * XP + col]     = l0;
        *(unsigned*)&xL[row * XP + col + 2] = l1;
    }
    __syncthreads();

    {
        int d = tid >> 4, part = tid & 15;
        float pxd = pxS[d], pyd = pyS[d];
        bool vd = vmS[d] > 0.5f;
        float deg = 0.f, s0 = 0.f, s1 = 0.f, s2 = 0.f;
        #pragma unroll
        for (int k = 0; k < 4; k++) {
            int s = part * 4 + k;
            float rx = pxd - pxS[s], ry = pyd - pyS[s];
            float dist = sqrtf(fmaxf(rx * rx + ry * ry, 1e-12f));
            bool adj = vd && (vmS[s] > 0.5f) && (dist < 0.3f) && (s != d);
            if (adj) { deg += 1.f; s0 += dist; s1 += rx; s2 += ry; }
        }
        #pragma unroll
        for (int off = 1; off < 16; off <<= 1) {
            deg += __shfl_xor(deg, off);
            s0  += __shfl_xor(s0, off);
            s1  += __shfl_xor(s1, off);
            s2  += __shfl_xor(s2, off);
        }
        if (part == 0) {
            float dg = fmaxf(deg, 1.f);
            loopS[d * 3 + 0] = s0 / dg;
            loopS[d * 3 + 1] = s1 / dg;
            loopS[d * 3 + 2] = s2 / dg;
        }
    }
    if (tid == 0) {
        float nv = 0.f;
        for (int m = 0; m < 64; m++) nv += vmS[m] > 0.5f ? 1.f : 0.f;
        nvS = fmaxf(nv, 1.f);
    }

    {
        f32x4 acc[4];
        #pragma unroll
        for (int mt = 0; mt < 4; mt++) acc[mt] = (f32x4){0.f, 0.f, 0.f, 0.f};
        for (int ks = 0; ks < 8; ks++) {
            const unsigned short* fb = &BswAll[((size_t)(ks * 16 + nt) * 64 + lane) * 16];
            bf16x8 bhi = *(const bf16x8*)&fb[0];
            bf16x8 blo = *(const bf16x8*)&fb[8];
            #pragma unroll
            for (int mt = 0; mt < 4; mt++) {
                int ao = (mt * 16 + ln15) * XP + ks * 32 + q * 8;
                bf16x8 ahi = *(const bf16x8*)&xH[ao];
                bf16x8 alo = *(const bf16x8*)&xL[ao];
                acc[mt] = __builtin_amdgcn_mfma_f32_16x16x32_bf16(ahi, bhi, acc[mt], 0, 0, 0);
                acc[mt] = __builtin_amdgcn_mfma_f32_16x16x32_bf16(alo, bhi, acc[mt], 0, 0, 0);
                acc[mt] = __builtin_amdgcn_mfma_f32_16x16x32_bf16(ahi, blo, acc[mt], 0, 0, 0);
            }
        }
        __syncthreads();
        int c = nt * 16 + ln15;
        float bv = inb[c];
        #pragma unroll
        for (int mt = 0; mt < 4; mt++) {
            #pragma unroll
            for (int r = 0; r < 4; r++) {
                int m = mt * 16 + q * 4 + r;
                float v = (acc[mt][r] + bv) * (vmS[m] > 0.5f ? 1.f : 0.f);
                unsigned short hi = f2bf(v);
                xH[m * XP + c] = hi;
                xL[m * XP + c] = f2bf(v - bf2f(hi));
            }
        }
    }
    __syncthreads();

    for (int l = 0; l < 3; l++) {
        const unsigned short* BswL = BswAll + (size_t)(1 + l) * 16384 * 16;
        const float* biasl = gbias + (size_t)l * 256;
        const float* lnsl  = glns + (size_t)l * 256;
        const float* lnbl  = glnb + (size_t)l * 256;
        const float* wES   = wESall + l * 12;

        f32x4 acc[4];
        #pragma unroll
        for (int mt = 0; mt < 4; mt++) acc[mt] = (f32x4){0.f, 0.f, 0.f, 0.f};
        for (int ks = 0; ks < 8; ks++) {
            const unsigned short* fb = &BswL[((size_t)(ks * 16 + nt) * 64 + lane) * 16];
            bf16x8 bhi = *(const bf16x8*)&fb[0];
            bf16x8 blo = *(const bf16x8*)&fb[8];
            #pragma unroll
            for (int mt = 0; mt < 4; mt++) {
                int ao = (mt * 16 + ln15) * XP + ks * 32 + q * 8;
                bf16x8 ahi = *(const bf16x8*)&xH[ao];
                bf16x8 alo = *(const bf16x8*)&xL[ao];
                acc[mt] = __builtin_amdgcn_mfma_f32_16x16x32_bf16(ahi, bhi, acc[mt], 0, 0, 0);
                acc[mt] = __builtin_amdgcn_mfma_f32_16x16x32_bf16(alo, bhi, acc[mt], 0, 0, 0);
                acc[mt] = __builtin_amdgcn_mfma_f32_16x16x32_bf16(ahi, blo, acc[mt], 0, 0, 0);
            }
        }

        if (w >= 12) {
            int mm = w - 12;
            f32x4 aax = (f32x4){0.f, 0.f, 0.f, 0.f};
            const unsigned short* AuxL = auxB + (size_t)l * 8 * 64 * 16;
            for (int ks = 0; ks < 8; ks++) {
                const unsigned short* fb = &AuxL[((size_t)ks * 64 + lane) * 16];
                bf16x8 bhi = *(const bf16x8*)&fb[0];
                bf16x8 blo = *(const bf16x8*)&fb[8];
                int ao = (mm * 16 + ln15) * XP + ks * 32 + q * 8;
                bf16x8 ahi = *(const bf16x8*)&xH[ao];
                bf16x8 alo = *(const bf16x8*)&xL[ao];
                aax = __builtin_amdgcn_mfma_f32_16x16x32_bf16(ahi, bhi, aax, 0, 0, 0);
                aax = __builtin_amdgcn_mfma_f32_16x16x32_bf16(alo, bhi, aax, 0, 0, 0);
                aax = __builtin_amdgcn_mfma_f32_16x16x32_bf16(ahi, blo, aax, 0, 0, 0);
            }
            if (ln15 < 4) {
                #pragma unroll
                for (int r = 0; r < 4; r++) asrcS[ln15][mm * 16 + q * 4 + r] = aax[r];
            } else if (ln15 < 8) {
                #pragma unroll
                for (int r = 0; r < 4; r++) adstS[ln15 - 4][mm * 16 + q * 4 + r] = aax[r];
            }
        }

        f32x4 macc[4];
        #pragma unroll
        for (int ct = 0; ct < 4; ct++) {
            int c = eh * 64 + ct * 16 + ln15;
            float bv = biasl[c];
            #pragma unroll
            for (int r = 0; r < 4; r++) {
                int d2 = dq * 16 + q * 4 + r;
                int o = d2 * XP + c;
                macc[ct][r] = bf2f(xH[o]) + bf2f(xL[o]) + bv;
            }
        }
        __syncthreads();

        {
            int c = nt * 16 + ln15;
            #pragma unroll
            for (int mt = 0; mt < 4; mt++) {
                unsigned p0 = cvt2(acc[mt][0], acc[mt][1]);
                unsigned p1 = cvt2(acc[mt][2], acc[mt][3]);
                float h0 = ubf(p0 << 16), h1 = ubf(p0 & 0xFFFF0000u);
                float h2 = ubf(p1 << 16), h3 = ubf(p1 & 0xFFFF0000u);
                unsigned l0 = cvt2(acc[mt][0] - h0, acc[mt][1] - h1);
                unsigned l1 = cvt2(acc[mt][2] - h2, acc[mt][3] - h3);
                int s = mt * 16 + q * 4;
                *(unsigned*)&U[c * 136 + s]          = p0;
                *(unsigned*)&U[c * 136 + s + 2]      = p1;
                *(unsigned*)&U[c * 136 + 64 + s]     = l0;
                *(unsigned*)&U[c * 136 + 64 + s + 2] = l1;
            }
        }
        __syncthreads();

        // Phase E: two-pass softmax (no lg array) + deferred normalization.
        {
            int d = dq * 16 + ln15;
            float pxd = pxS[d], pyd = pyS[d];
            bool vdv = vmS[d] > 0.5f;
            float adstv = adstS[eh][d];
            float lp0 = loopS[d * 3 + 0];
            float lp1 = loopS[d * 3 + 1];
            float lp2 = loopS[d * 3 + 2];
            float we0 = wES[eh], we1 = wES[4 + eh], we2 = wES[8 + eh];

            // identical logit computation for both passes
            auto logit = [&](int s, float px, float py, float vm, float as) -> float {
                float rx = pxd - px, ry = pyd - py;
                float dist = sqrtf(fmaxf(rx * rx + ry * ry, 1e-12f));
                bool self = (s == d);
                bool adj = vdv && (vm > 0.5f) && (dist < 0.3f) && !self;
                float e0 = adj ? dist : (self ? lp0 : 0.f);
                float e1 = adj ? rx   : (self ? lp1 : 0.f);
                float e2 = adj ? ry   : (self ? lp2 : 0.f);
                bool fa = adj || (self && vdv);
                float lv = as + adstv + e0 * we0 + e1 * we1 + e2 * we2;
                lv = lv >= 0.f ? lv : 0.2f * lv;
                return fa ? lv : -1e9f;
            };

            // pass 1: max only
            float mx = -1e30f;
            #pragma unroll
            for (int ks = 0; ks < 2; ks++) {
                int s0 = ks * 32 + q * 8;
                F8 PX, PY, VM, AS;
                PX.v2[0] = *(const float4*)&pxS[s0]; PX.v2[1] = *(const float4*)&pxS[s0 + 4];
                PY.v2[0] = *(const float4*)&pyS[s0]; PY.v2[1] = *(const float4*)&pyS[s0 + 4];
                VM.v2[0] = *(const float4*)&vmS[s0]; VM.v2[1] = *(const float4*)&vmS[s0 + 4];
                AS.v2[0] = *(const float4*)&asrcS[eh][s0];
                AS.v2[1] = *(const float4*)&asrcS[eh][s0 + 4];
                #pragma unroll
                for (int j = 0; j < 8; j++)
                    mx = fmaxf(mx, logit(s0 + j, PX.f[j], PY.f[j], VM.f[j], AS.f[j]));
            }
            mx = fmaxf(mx, __shfl_xor(mx, 16));
            mx = fmaxf(mx, __shfl_xor(mx, 32));

            // pass 2: recompute, exp, accumulate sm, pack UNNORMALIZED alpha
            float sm = 0.f;
            bf16x8 ah[2], al[2];
            #pragma unroll
            for (int ks = 0; ks < 2; ks++) {
                int s0 = ks * 32 + q * 8;
                F8 PX, PY, VM, AS;
                PX.v2[0] = *(const float4*)&pxS[s0]; PX.v2[1] = *(const float4*)&pxS[s0 + 4];
                PY.v2[0] = *(const float4*)&pyS[s0]; PY.v2[1] = *(const float4*)&pyS[s0 + 4];
                VM.v2[0] = *(const float4*)&vmS[s0]; VM.v2[1] = *(const float4*)&vmS[s0 + 4];
                AS.v2[0] = *(const float4*)&asrcS[eh][s0];
                AS.v2[1] = *(const float4*)&asrcS[eh][s0 + 4];
                union { bf16x8 v; unsigned u[4]; } H, L;
                #pragma unroll
                for (int jj = 0; jj < 4; jj++) {
                    int j0 = jj * 2, j1 = jj * 2 + 1;
                    float e0 = __expf(logit(s0 + j0, PX.f[j0], PY.f[j0], VM.f[j0], AS.f[j0]) - mx);
                    float e1 = __expf(logit(s0 + j1, PX.f[j1], PY.f[j1], VM.f[j1], AS.f[j1]) - mx);
                    sm += e0 + e1;
                    unsigned p = cvt2(e0, e1);
                    H.u[jj] = p;
                    float f0 = ubf(p << 16), f1 = ubf(p & 0xFFFF0000u);
                    L.u[jj] = cvt2(e0 - f0, e1 - f1);
                }
                ah[ks] = H.v; al[ks] = L.v;
            }
            sm += __shfl_xor(sm, 16);
            sm += __shfl_xor(sm, 32);
            float inv = 1.f / sm;

            // per-C-row sm / inv (C row = q*4 + r; that row's sm lives in lane q*4+r)
            float smr[4], invr[4];
            #pragma unroll
            for (int r = 0; r < 4; r++) {
                smr[r]  = __shfl(sm,  q * 4 + r);
                invr[r] = __shfl(inv, q * 4 + r);
            }
            #pragma unroll
            for (int ct = 0; ct < 4; ct++)
                #pragma unroll
                for (int r = 0; r < 4; r++) macc[ct][r] *= smr[r];

            // PV MFMA with unnormalized alpha
            #pragma unroll
            for (int ks2 = 0; ks2 < 2; ks2++) {
                #pragma unroll
                for (int ct = 0; ct < 4; ct++) {
                    const unsigned short* hb =
                        &U[(size_t)(eh * 64 + ct * 16 + ln15) * 136 + ks2 * 32 + q * 8];
                    bf16x8 bhi = *(const bf16x8*)&hb[0];
                    bf16x8 blo = *(const bf16x8*)&hb[64];
                    macc[ct] = __builtin_amdgcn_mfma_f32_16x16x32_bf16(ah[ks2], bhi, macc[ct], 0, 0, 0);
                    macc[ct] = __builtin_amdgcn_mfma_f32_16x16x32_bf16(al[ks2], bhi, macc[ct], 0, 0, 0);
                    macc[ct] = __builtin_amdgcn_mfma_f32_16x16x32_bf16(ah[ks2], blo, macc[ct], 0, 0, 0);
                }
            }
            #pragma unroll
            for (int ct = 0; ct < 4; ct++)
                #pragma unroll
                for (int r = 0; r < 4; r++) macc[ct][r] *= invr[r];
        }

        {
            float scv[4], bbv[4];
            #pragma unroll
            for (int ct = 0; ct < 4; ct++) {
                int c = eh * 64 + ct * 16 + ln15;
                scv[ct] = lnsl[c];
                bbv[ct] = lnbl[c];
            }
            float ps[4], ps2[4];
            #pragma unroll
            for (int r = 0; r < 4; r++) {
                float s = 0.f, s2 = 0.f;
                #pragma unroll
                for (int ct = 0; ct < 4; ct++) {
                    float v = macc[ct][r];
                    s += v; s2 += v * v;
                }
                ps[r] = s; ps2[r] = s2;
            }
            #pragma unroll
            for (int off = 1; off < 16; off <<= 1) {
                #pragma unroll
                for (int i = 0; i < 4; i++) {
                    ps[i]  += __shfl_xor(ps[i], off);
                    ps2[i] += __shfl_xor(ps2[i], off);
                }
            }
            if (ln15 == 0) {
                #pragma unroll
                for (int r = 0; r < 4; r++) {
                    int d2 = dq * 16 + q * 4 + r;
                    sumsS[d2][eh * 2 + 0] = ps[r];
                    sumsS[d2][eh * 2 + 1] = ps2[r];
                }
            }
            __syncthreads();
            if (tid < 64) {
                float S  = sumsS[tid][0] + sumsS[tid][2] + sumsS[tid][4] + sumsS[tid][6];
                float S2 = sumsS[tid][1] + sumsS[tid][3] + sumsS[tid][5] + sumsS[tid][7];
                float mu = S * (1.f / 256.f);
                float var = S2 * (1.f / 256.f) - mu * mu;
                mrsS[tid][0] = mu;
                mrsS[tid][1] = rsqrtf(var + 1e-5f);
            }
            __syncthreads();
            #pragma unroll
            for (int r = 0; r < 4; r++) {
                int d2 = dq * 16 + q * 4 + r;
                float mu = mrsS[d2][0], rs = mrsS[d2][1];
                #pragma unroll
                for (int ct = 0; ct < 4; ct++) {
                    float v = (macc[ct][r] - mu) * rs * scv[ct] + bbv[ct];
                    v = fmaxf(v, 0.f);
                    unsigned short hi = f2bf(v);
                    int o = d2 * XP + eh * 64 + ct * 16 + ln15;
                    xH[o] = hi;
                    xL[o] = f2bf(v - bf2f(hi));
                }
            }
        }
        __syncthreads();
    }

    if (tid < 256) {
        float s = 0.f;
        for (int m = 0; m < 64; m++) {
            float xv = bf2f(xH[m * XP + tid]) + bf2f(xL[m * XP + tid]);
            s += xv * (vmS[m] > 0.5f ? 1.f : 0.f);
        }
        framebuf[(size_t)bt * 256 + tid] = s / nvS;
    }
}

// ---------------------------------------------------------------------------
// Unified MFMA tile-GEMM for the transformer tail (unchanged from round 6).
#define TG_RELU 1
#define TG_RES  2
#define XPA 264
__global__ __launch_bounds__(256, 4) void k_tgemm(const float* __restrict__ A,
                                                  const float* __restrict__ lnS,
                                                  const float* __restrict__ lnB,
                                                  const float* __restrict__ W,
                                                  const float* __restrict__ bias,
                                                  const float* __restrict__ pe,
                                                  float* __restrict__ out,
                                                  int K, int N, int ldo, int flags) {
    __shared__ __align__(16) unsigned short AH[64 * XPA];
    __shared__ __align__(16) unsigned short AL[64 * XPA];

    int tid = threadIdx.x;
    int lane = tid & 63, w = tid >> 6;
    int ln15 = lane & 15, q = lane >> 4;
    int Mbase = blockIdx.x * 64;
    int Nbase = blockIdx.y * 64;
    int r = tid >> 2, p = tid & 3;    // staging: row r, quarter p

    f32x4 acc[4];
    #pragma unroll
    for (int mt = 0; mt < 4; mt++) acc[mt] = (f32x4){0.f, 0.f, 0.f, 0.f};

    int nchunks = K >> 8;             // 1 (K=256) or 2 (K=512)
    for (int kc = 0; kc < nchunks; kc++) {
        {
            const float* arow = A + (size_t)(Mbase + r) * K + kc * 256 + p * 4;
            if (lnS && kc == 0) {
                float s = 0.f, s2 = 0.f;
                #pragma unroll
                for (int j = 0; j < 16; j++) {
                    float4 v = *(const float4*)&arow[j * 16];
                    s  += v.x + v.y + v.z + v.w;
                    s2 += v.x * v.x + v.y * v.y + v.z * v.z + v.w * v.w;
                }
                s  += __shfl_xor(s, 1);  s  += __shfl_xor(s, 2);
                s2 += __shfl_xor(s2, 1); s2 += __shfl_xor(s2, 2);
                float mu = s * (1.f / 256.f);
                float var = s2 * (1.f / 256.f) - mu * mu;
                float rstd = rsqrtf(var + 1e-5f);
                #pragma unroll
                for (int j = 0; j < 16; j++) {
                    int c = p * 4 + j * 16;
                    float4 v = *(const float4*)&arow[j * 16];
                    float4 ls = *(const float4*)&lnS[c];
                    float4 lb = *(const float4*)&lnB[c];
                    float4 z;
                    z.x = (v.x - mu) * rstd * ls.x + lb.x;
                    z.y = (v.y - mu) * rstd * ls.y + lb.y;
                    z.z = (v.z - mu) * rstd * ls.z + lb.z;
                    z.w = (v.w - mu) * rstd * ls.w + lb.w;
                    unsigned p0 = cvt2(z.x, z.y), p1 = cvt2(z.z, z.w);
                    float f0 = ubf(p0 << 16), f1 = ubf(p0 & 0xFFFF0000u);
                    float f2 = ubf(p1 << 16), f3 = ubf(p1 & 0xFFFF0000u);
                    unsigned l0 = cvt2(z.x - f0, z.y - f1);
                    unsigned l1 = cvt2(z.z - f2, z.w - f3);
                    *(unsigned*)&AH[r * XPA + c]     = p0;
                    *(unsigned*)&AH[r * XPA + c + 2] = p1;
                    *(unsigned*)&AL[r * XPA + c]     = l0;
                    *(unsigned*)&AL[r * XPA + c + 2] = l1;
                }
            } else {
                #pragma unroll
                for (int j = 0; j < 16; j++) {
                    int c = p * 4 + j * 16;
                    float4 v = *(const float4*)&arow[j * 16];
                    unsigned p0 = cvt2(v.x, v.y), p1 = cvt2(v.z, v.w);
                    float f0 = ubf(p0 << 16), f1 = ubf(p0 & 0xFFFF0000u);
                    float f2 = ubf(p1 << 16), f3 = ubf(p1 & 0xFFFF0000u);
                    unsigned l0 = cvt2(v.x - f0, v.y - f1);
                    unsigned l1 = cvt2(v.z - f2, v.w - f3);
                    *(unsigned*)&AH[r * XPA + c]     = p0;
                    *(unsigned*)&AH[r * XPA + c + 2] = p1;
                    *(unsigned*)&AL[r * XPA + c]     = l0;
                    *(unsigned*)&AL[r * XPA + c + 2] = l1;
                }
            }
        }
        __syncthreads();

        const float* wrow = W + (size_t)(Nbase + w * 16 + ln15) * K + kc * 256 + q * 8;
        for (int ks = 0; ks < 8; ks++) {
            float4 b0 = *(const float4*)&wrow[ks * 32];
            float4 b1 = *(const float4*)&wrow[ks * 32 + 4];
            unsigned h0 = cvt2(b0.x, b0.y), h1 = cvt2(b0.z, b0.w);
            unsigned h2 = cvt2(b1.x, b1.y), h3 = cvt2(b1.z, b1.w);
            float g0 = ubf(h0 << 16), g1 = ubf(h0 & 0xFFFF0000u);
            float g2 = ubf(h1 << 16), g3 = ubf(h1 & 0xFFFF0000u);
            float g4 = ubf(h2 << 16), g5 = ubf(h2 & 0xFFFF0000u);
            float g6 = ubf(h3 << 16), g7 = ubf(h3 & 0xFFFF0000u);
            union { bf16x8 v; unsigned u[4]; } BH, BL;
            BH.u[0] = h0; BH.u[1] = h1; BH.u[2] = h2; BH.u[3] = h3;
            BL.u[0] = cvt2(b0.x - g0, b0.y - g1);
            BL.u[1] = cvt2(b0.z - g2, b0.w - g3);
            BL.u[2] = cvt2(b1.x - g4, b1.y - g5);
            BL.u[3] = cvt2(b1.z - g6, b1.w - g7);
            bf16x8 bhi = BH.v, blo = BL.v;
            #pragma unroll
            for (int mt = 0; mt < 4; mt++) {
                int ao = (mt * 16 + ln15) * XPA + ks * 32 + q * 8;
                bf16x8 ahi = *(const bf16x8*)&AH[ao];
                bf16x8 alo = *(const bf16x8*)&AL[ao];
                acc[mt] = __builtin_amdgcn_mfma_f32_16x16x32_bf16(ahi, bhi, acc[mt], 0, 0, 0);
                acc[mt] = __builtin_amdgcn_mfma_f32_16x16x32_bf16(alo, bhi, acc[mt], 0, 0, 0);
                acc[mt] = __builtin_amdgcn_mfma_f32_16x16x32_bf16(ahi, blo, acc[mt], 0, 0, 0);
            }
        }
        if (kc + 1 < nchunks) __syncthreads();
    }

    int n = Nbase + w * 16 + ln15;
    float bv = bias[n];
    #pragma unroll
    for (int mt = 0; mt < 4; mt++) {
        #pragma unroll
        for (int rr = 0; rr < 4; rr++) {
            int row = Mbase + mt * 16 + q * 4 + rr;
            float v = acc[mt][rr] + bv;
            if (pe) v += pe[(row & 31) * 256 + n];
            size_t oidx = (size_t)row * ldo + n;
            if (flags & TG_RES) v += out[oidx];
            if (flags & TG_RELU) v = fmaxf(v, 0.f);
            out[oidx] = v;
        }
    }
}

// ---------------------------------------------------------------------------
__global__ __launch_bounds__(64) void k_attn(const float* __restrict__ qkvbuf,
                                             float* __restrict__ obuf) {
    int blk = blockIdx.x;
    int b = blk >> 3, h = blk & 7;
    int tid = threadIdx.x;
    __shared__ float Ks[32 * 32], Vs[32 * 32];
    for (int idx = tid; idx < 1024; idx += 64) {
        int tk = idx >> 5, c = idx & 31;
        size_t qbase = ((size_t)(b * 32 + tk)) * 768 + h * 32 + c;
        Ks[idx] = qkvbuf[qbase + 256];
        Vs[idx] = qkvbuf[qbase + 512];
    }
    __syncthreads();
    if (tid < 32) {
        int tq = tid;
        float qv[32];
        size_t qb0 = ((size_t)(b * 32 + tq)) * 768 + h * 32;
        #pragma unroll
        for (int c = 0; c < 32; c++) qv[c] = qkvbuf[qb0 + c];
        float scr[32];
        float mx = -1e30f;
        #pragma unroll
        for (int tk = 0; tk < 32; tk++) {
            float dd = 0.f;
            #pragma unroll
            for (int c = 0; c < 32; c++) dd = fmaf(qv[c], Ks[tk * 32 + c], dd);
            dd *= 0.17677669529663687f;
            scr[tk] = dd;
            mx = fmaxf(mx, dd);
        }
        float sm = 0.f;
        #pragma unroll
        for (int tk = 0; tk < 32; tk++) { scr[tk] = __expf(scr[tk] - mx); sm += scr[tk]; }
        float inv = 1.f / sm;
        float o[32];
        #pragma unroll
        for (int c = 0; c < 32; c++) o[c] = 0.f;
        #pragma unroll
        for (int tk = 0; tk < 32; tk++) {
            float a = scr[tk] * inv;
            #pragma unroll
            for (int c = 0; c < 32; c++) o[c] = fmaf(a, Vs[tk * 32 + c], o[c]);
        }
        size_t ob = ((size_t)(b * 32 + tq)) * 256 + h * 32;
        #pragma unroll
        for (int c = 0; c < 32; c++) obuf[ob + c] = o[c];
    }
}

// ---------------------------------------------------------------------------
__global__ __launch_bounds__(256) void k_pool_out(const float* __restrict__ ybuf,
                                                  const float* __restrict__ pW,
                                                  const float* __restrict__ pb,
                                                  const float* __restrict__ oW,
                                                  const float* __restrict__ ob,
                                                  const float* __restrict__ lns,
                                                  const float* __restrict__ lnb,
                                                  float* __restrict__ dout) {
    int b = blockIdx.x, tid = threadIdx.x;
    __shared__ float redP[256];
    __shared__ float wS[32];
    __shared__ float pS[256];
    __shared__ float red[8];
    int tq = tid >> 3, part = tid & 7;
    float partial = 0.f;
    {
        const float* yrow = ybuf + ((size_t)(b * 32 + tq)) * 256 + part * 32;
        const float* pwp = pW + part * 32;
        #pragma unroll
        for (int j = 0; j < 32; j += 4) {
            float4 yv = *(const float4*)&yrow[j];
            float4 wv = *(const float4*)&pwp[j];
            partial += dot4(yv, wv);
        }
    }
    redP[tid] = partial;
    __syncthreads();
    if (tid < 32) {
        float s = pb[0];
        for (int p = 0; p < 8; p++) s += redP[tid * 8 + p];
        float mx = s;
        #pragma unroll
        for (int off = 16; off; off >>= 1) mx = fmaxf(mx, __shfl_xor(mx, off));
        float e = __expf(s - mx);
        float sm = e;
        #pragma unroll
        for (int off = 16; off; off >>= 1) sm += __shfl_xor(sm, off);
        wS[tid] = e / sm;
    }
    __syncthreads();
    float p = 0.f;
    for (int t = 0; t < 32; t++) p += ybuf[((size_t)(b * 32 + t)) * 256 + tid] * wS[t];
    pS[tid] = p;
    __syncthreads();
    float accs[2];
    for (int r = 0; r < 2; r++) {
        int j = r * 256 + tid;
        float acc = ob[j];
        const float* wrow = oW + (size_t)j * 256;
        for (int g = 0; g < 256; g += 4) {
            float4 pv = *(const float4*)&pS[g];
            float4 wv = *(const float4*)&wrow[g];
            acc += dot4(pv, wv);
        }
        accs[r] = acc;
    }
    float s = accs[0] + accs[1];
    float s2 = accs[0] * accs[0] + accs[1] * accs[1];
    #pragma unroll
    for (int off = 32; off; off >>= 1) {
        s += __shfl_xor(s, off);
        s2 += __shfl_xor(s2, off);
    }
    int wid = threadIdx.x >> 6;
    int lane = threadIdx.x & 63;
    if (lane == 0) { red[wid] = s; red[4 + wid] = s2; }
    __syncthreads();
    s = red[0] + red[1] + red[2] + red[3];
    s2 = red[4] + red[5] + red[6] + red[7];
    float mu = s * (1.f / 512.f);
    float var = s2 * (1.f / 512.f) - mu * mu;
    float rstd = rsqrtf(var + 1e-5f);
    dout[b * 512 + tid]       = fmaxf((accs[0] - mu) * rstd * lns[tid] + lnb[tid], 0.f);
    dout[b * 512 + tid + 256] = fmaxf((accs[1] - mu) * rstd * lns[tid + 256] + lnb[tid + 256], 0.f);
}

// ---------------------------------------------------------------------------
extern "C" void kernel_launch(void* const* d_in, const int* in_sizes, int n_in,
                              void* d_out, int out_size, void* d_ws, size_t ws_size,
                              hipStream_t stream) {
    const float* drone_feats = (const float*)d_in[0];
    const float* boxes       = (const float*)d_in[1];
    const float* drone_mask  = (const float*)d_in[2];
    const float* in_proj_W   = (const float*)d_in[3];
    const float* in_proj_b   = (const float*)d_in[4];
    const float* gat_lin_W   = (const float*)d_in[5];
    const float* gat_edge_W  = (const float*)d_in[6];
    const float* gat_att_src = (const float*)d_in[7];
    const float* gat_att_dst = (const float*)d_in[8];
    const float* gat_att_edge= (const float*)d_in[9];
    const float* gat_bias    = (const float*)d_in[10];
    const float* gat_ln_s    = (const float*)d_in[11];
    const float* gat_ln_b    = (const float*)d_in[12];
    const float* temp_W      = (const float*)d_in[13];
    const float* temp_b      = (const float*)d_in[14];
    const float* pos_emb     = (const float*)d_in[15];
    const float* qkv_W       = (const float*)d_in[16];
    const float* qkv_b       = (const float*)d_in[17];
    const float* attn_out_W  = (const float*)d_in[18];
    const float* attn_out_b  = (const float*)d_in[19];
    const float* ln1_s       = (const float*)d_in[20];
    const float* ln1_b       = (const float*)d_in[21];
    const float* ln2_s       = (const float*)d_in[22];
    const float* ln2_b       = (const float*)d_in[23];
    const float* ff1_W       = (const float*)d_in[24];
    const float* ff1_b       = (const float*)d_in[25];
    const float* ff2_W       = (const float*)d_in[26];
    const float* ff2_b       = (const float*)d_in[27];
    const float* pool_W      = (const float*)d_in[28];
    const float* pool_b      = (const float*)d_in[29];
    const float* out_W       = (const float*)d_in[30];
    const float* out_b       = (const float*)d_in[31];
    const float* out_ln_s    = (const float*)d_in[32];
    const float* out_ln_b    = (const float*)d_in[33];
    float* out = (float*)d_out;

    float* ws = (float*)d_ws;
    unsigned short* Bsw    = (unsigned short*)ws;                 // 4*16384*16 ush = 2 MB
    unsigned short* BswAux = Bsw + (size_t)4 * 16384 * 16;        // 3*8*64*16 ush = 48 KB
    size_t off = ((size_t)4 * 16384 * 16 + 3 * 8 * 64 * 16 + 1) / 2;  // floats
    float* framebuf = ws + off; off += (size_t)BT * 256;
    float* ybuf   = ws + off; off += (size_t)BT * 256;
    float* qkvbuf = ws + off; off += (size_t)BT * 768;
    float* obuf   = ws + off; off += (size_t)BT * 256;
    float* fbuf   = ws + off; off += (size_t)BT * 512;

    k_prep<<<dim3(256), dim3(256), 0, stream>>>(in_proj_W, gat_lin_W, Bsw);
    k_prep_aux<<<dim3(24), dim3(64), 0, stream>>>(gat_lin_W, gat_att_src, gat_att_dst, BswAux);
    k_gnn<<<dim3(BT), dim3(1024), 0, stream>>>(drone_feats, boxes, drone_mask, Bsw, BswAux,
        in_proj_b, gat_edge_W, gat_att_edge,
        gat_bias, gat_ln_s, gat_ln_b, framebuf);
    // temp proj + pos_emb: ybuf = framebuf @ temp_W^T + temp_b + pe
    k_tgemm<<<dim3(BT / 64, 4), dim3(256), 0, stream>>>(framebuf, nullptr, nullptr,
        temp_W, temp_b, pos_emb, ybuf, 256, 256, 256, 0);
    for (int l = 0; l < 2; l++) {
        // qkv = LN1(y) @ qkv_W^T + qkv_b
        k_tgemm<<<dim3(BT / 64, 12), dim3(256), 0, stream>>>(ybuf,
            ln1_s + l * 256, ln1_b + l * 256,
            qkv_W + (size_t)l * 768 * 256, qkv_b + l * 768, nullptr,
            qkvbuf, 256, 768, 768, 0);
        k_attn<<<dim3(512), dim3(64), 0, stream>>>(qkvbuf, obuf);
        // y += o @ ao_W^T + ao_b
        k_tgemm<<<dim3(BT / 64, 4), dim3(256), 0, stream>>>(obuf, nullptr, nullptr,
            attn_out_W + (size_t)l * 65536, attn_out_b + l * 256, nullptr,
            ybuf, 256, 256, 256, TG_RES);
        // f = relu(LN2(y) @ ff1_W^T + ff1_b)
        k_tgemm<<<dim3(BT / 64, 8), dim3(256), 0, stream>>>(ybuf,
            ln2_s + l * 256, ln2_b + l * 256,
            ff1_W + (size_t)l * 131072, ff1_b + l * 512, nullptr,
            fbuf, 256, 512, 512, TG_RELU);
        // y += f @ ff2_W^T + ff2_b
        k_tgemm<<<dim3(BT / 64, 4), dim3(256), 0, stream>>>(fbuf, nullptr, nullptr,
            ff2_W + (size_t)l * 131072, ff2_b + l * 256, nullptr,
            ybuf, 512, 256, 256, TG_RES);
    }
    k_pool_out<<<dim3(64), dim3(256), 0, stream>>>(ybuf, pool_W, pool_b, out_W, out_b,
                                                   out_ln_s, out_ln_b, out);
}

// Round 9
// 935.906 us; speedup vs baseline: 1.3087x; 1.3087x over previous
//
#include <hip/hip_runtime.h>
#include <math.h>

#define BT 2048

typedef __attribute__((ext_vector_type(8))) short bf16x8;
typedef __attribute__((ext_vector_type(4))) float f32x4;
typedef __attribute__((ext_vector_type(4))) unsigned short u16x4;

__device__ inline unsigned short f2bf(float f) {
    union { float f; unsigned u; } v; v.f = f;
    unsigned r = (v.u >> 16) & 1u;
    return (unsigned short)((v.u + 0x7FFFu + r) >> 16);
}
__device__ inline float bf2f(unsigned short s) {
    union { unsigned u; float f; } v; v.u = ((unsigned)s) << 16;
    return v.f;
}
__device__ inline float ubf(unsigned u) {
    union { unsigned u; float f; } v; v.u = u; return v.f;
}
// HW packed convert: lo16 = bf16(a), hi16 = bf16(b). Single VALU op.
__device__ inline unsigned cvt2(float a, float b) {
    unsigned r;
    asm("v_cvt_pk_bf16_f32 %0, %1, %2" : "=v"(r) : "v"(a), "v"(b));
    return r;
}

__device__ inline float dot4(const float4 a, const float4 b) {
    return fmaf(a.x, b.x, fmaf(a.y, b.y, fmaf(a.z, b.z, a.w * b.w)));
}

union F8 { float4 v2[2]; float f[8]; };

// x/feats LDS planes: [64 rows][264 cols] ushort (pad 8 cols kills stride-256 conflicts)
#define XP 264

// ---------------------------------------------------------------------------
// Pre-swizzle GNN weights into MFMA B-fragment order, SPLIT bf16 hi/lo.
__global__ __launch_bounds__(256) void k_prep(const float* __restrict__ inW,
                                              const float* __restrict__ gatW,
                                              unsigned short* __restrict__ dst) {
    int gid = blockIdx.x * 256 + threadIdx.x;   // 0..65535
    int mat = gid >> 14;
    int r   = gid & 16383;
    int ks  = r >> 10;
    int nt  = (r >> 6) & 15;
    int lane = r & 63;
    int ln15 = lane & 15, q = lane >> 4;
    int n  = nt * 16 + ln15;
    int k0 = ks * 32 + q * 8;
    const float* src; bool tr;
    if (mat == 0) { src = inW; tr = true; }
    else          { src = gatW + (size_t)(mat - 1) * 65536; tr = false; }
    unsigned short* d = dst + ((size_t)mat * 16384 + r) * 16;
    if (ks < 8) {
        #pragma unroll
        for (int j = 0; j < 8; j++) {
            float v = tr ? src[n * 256 + k0 + j] : src[(size_t)(k0 + j) * 256 + n];
            unsigned short hi = f2bf(v);
            d[j]     = hi;
            d[8 + j] = f2bf(v - bf2f(hi));
        }
    } else {
        #pragma unroll
        for (int j = 0; j < 8; j++) { d[j] = 0; d[8 + j] = 0; }
    }
}

// ---------------------------------------------------------------------------
// Aux B-tiles: a_src = x @ (W . att_src) folded into the phase-B GEMM.
__global__ __launch_bounds__(64) void k_prep_aux(const float* __restrict__ gatW,
                                                 const float* __restrict__ attS,
                                                 const float* __restrict__ attD,
                                                 unsigned short* __restrict__ dst) {
    int l  = blockIdx.x >> 3;      // 0..2
    int ks = blockIdx.x & 7;       // 0..7
    int lane = threadIdx.x;
    int ln15 = lane & 15, q = lane >> 4;
    int k0 = ks * 32 + q * 8;
    const float* W = gatW + (size_t)l * 65536;
    unsigned short* d = dst + ((size_t)(l * 8 + ks) * 64 + lane) * 16;
    #pragma unroll
    for (int j = 0; j < 8; j++) {
        float v = 0.f;
        if (ln15 < 8) {
            int head = ln15 & 3;
            const float* a = (ln15 < 4 ? attS : attD) + (size_t)l * 256 + head * 64;
            const float* wr = W + (size_t)(k0 + j) * 256 + head * 64;
            for (int c = 0; c < 64; c++) v = fmaf(wr[c], a[c], v);
        }
        unsigned short hi = f2bf(v);
        d[j]     = hi;
        d[8 + j] = f2bf(v - bf2f(hi));
    }
}

// ---------------------------------------------------------------------------
// Pre-swizzle TAIL weights (W row-major [N][K] fp32) into fragment layout:
// frag idx = ((ks*(N/16) + nt)*64 + lane)*16, hi[0..7] lo[8..15].
// One kernel, blockIdx ranges select the matrix. 64 threads = 1 (ks,nt) pair.
__global__ __launch_bounds__(64) void k_prep_tail(const float* __restrict__ tempW,
                                                  const float* __restrict__ qkvW,
                                                  const float* __restrict__ aoW,
                                                  const float* __restrict__ ff1W,
                                                  const float* __restrict__ ff2W,
                                                  unsigned short* __restrict__ dst) {
    int b = blockIdx.x;
    const float* W; int K, N; size_t foff; int rel;
    if (b < 128)        { W = tempW;                       K = 256; N = 256; foff = 0;      rel = b; }
    else if (b < 512)   { W = qkvW;                        K = 256; N = 768; foff = 8192;   rel = b - 128; }
    else if (b < 896)   { W = qkvW + (size_t)768 * 256;    K = 256; N = 768; foff = 32768;  rel = b - 512; }
    else if (b < 1024)  { W = aoW;                         K = 256; N = 256; foff = 57344;  rel = b - 896; }
    else if (b < 1152)  { W = aoW + (size_t)256 * 256;     K = 256; N = 256; foff = 65536;  rel = b - 1024; }
    else if (b < 1408)  { W = ff1W;                        K = 256; N = 512; foff = 73728;  rel = b - 1152; }
    else if (b < 1664)  { W = ff1W + (size_t)512 * 256;    K = 256; N = 512; foff = 90112;  rel = b - 1408; }
    else if (b < 1920)  { W = ff2W;                        K = 512; N = 256; foff = 106496; rel = b - 1664; }
    else                { W = ff2W + (size_t)256 * 512;    K = 512; N = 256; foff = 122880; rel = b - 1920; }
    int nt16 = N >> 4;
    int ks = rel / nt16, nt = rel - ks * nt16;
    int lane = threadIdx.x;
    int ln15 = lane & 15, q = lane >> 4;
    int n = nt * 16 + ln15;
    int k0 = ks * 32 + q * 8;
    unsigned short* d = dst + (foff + ((size_t)rel * 64 + lane)) * 16;
    #pragma unroll
    for (int j = 0; j < 8; j++) {
        float v = W[(size_t)n * K + k0 + j];
        unsigned short hi = f2bf(v);
        d[j]     = hi;
        d[8 + j] = f2bf(v - bf2f(hi));
    }
}

// ---------------------------------------------------------------------------
// Fully fused GNN — EXACT round-6 body (measured 619/623 us twice). The r7
// two-pass-softmax "register diet" regressed to 876 us (spill grew); reverted.
__global__ __launch_bounds__(1024, 8) void k_gnn(const float* __restrict__ feats,
                                                 const float* __restrict__ boxes,
                                                 const float* __restrict__ maskp,
                                                 const unsigned short* __restrict__ BswAll,
                                                 const unsigned short* __restrict__ auxB,
                                                 const float* __restrict__ inb,
                                                 const float* __restrict__ edgeW,
                                                 const float* __restrict__ attEg,
                                                 const float* __restrict__ gbias,
                                                 const float* __restrict__ glns,
                                                 const float* __restrict__ glnb,
                                                 float* __restrict__ framebuf) {
    int bt = blockIdx.x;
    size_t fbase = (size_t)bt * 64 * 256;

    __shared__ __align__(16) unsigned short U[256 * 136]; // x planes OR hT (aliased)
    __shared__ float pxS[64], pyS[64], vmS[64];
    __shared__ float loopS[192];
    __shared__ float asrcS[4][64], adstS[4][64];  // PER-HEAD (from aux MFMA)
    __shared__ float wESall[36];                  // [l][e][h]
    __shared__ float sumsS[64][8];                // [d][head*2 + {sum,sum2}]
    __shared__ float mrsS[64][2];
    __shared__ float nvS;

    unsigned short* xH = U;                 // x hi plane [64][XP]
    unsigned short* xL = U + 64 * XP;       // x lo plane

    int tid = threadIdx.x, lane = tid & 63, w = tid >> 6;   // w 0..15
    int ln15 = lane & 15, q = lane >> 4;
    int nt = w;
    int eh = w >> 2;
    int dq = w & 3;

    if (tid < 64) {
        const float* bx = boxes + (size_t)(bt * 64 + tid) * 5;
        pxS[tid] = bx[1];
        pyS[tid] = bx[2];
        vmS[tid] = maskp[bt * 64 + tid];
    } else if (tid < 100) {
        int idx = tid - 64;
        int l = idx / 12, r2 = idx - l * 12;
        int e = r2 >> 2, h2 = r2 & 3;
        float sm = 0.f;
        const float* ew = edgeW + (size_t)l * 768 + e * 256 + h2 * 64;
        const float* ae = attEg + (size_t)l * 256 + h2 * 64;
        for (int c = 0; c < 64; c++) sm += ew[c] * ae[c];
        wESall[idx] = sm;
    }
    #pragma unroll
    for (int j = 0; j < 4; j++) {
        int g = j * 4096 + tid * 4;
        int row = g >> 8, col = g & 255;
        float4 v4 = *(const float4*)&feats[fbase + g];
        unsigned p0 = cvt2(v4.x, v4.y);
        unsigned p1 = cvt2(v4.z, v4.w);
        float h0 = ubf(p0 << 16), h1 = ubf(p0 & 0xFFFF0000u);
        float h2 = ubf(p1 << 16), h3 = ubf(p1 & 0xFFFF0000u);
        unsigned l0 = cvt2(v4.x - h0, v4.y - h1);
        unsigned l1 = cvt2(v4.z - h2, v4.w - h3);
        *(unsigned*)&xH[row * XP + col]     = p0;
        *(unsigned*)&xH[row * XP + col + 2] = p1;
        *(unsigned*)&xL[row * XP + col]     = l0;
        *(unsigned*)&xL[row * XP + col + 2] = l1;
    }
    __syncthreads();

    {
        int d = tid >> 4, part = tid & 15;
        float pxd = pxS[d], pyd = pyS[d];
        bool vd = vmS[d] > 0.5f;
        float deg = 0.f, s0 = 0.f, s1 = 0.f, s2 = 0.f;
        #pragma unroll
        for (int k = 0; k < 4; k++) {
            int s = part * 4 + k;
            float rx = pxd - pxS[s], ry = pyd - pyS[s];
            float dist = sqrtf(fmaxf(rx * rx + ry * ry, 1e-12f));
            bool adj = vd && (vmS[s] > 0.5f) && (dist < 0.3f) && (s != d);
            if (adj) { deg += 1.f; s0 += dist; s1 += rx; s2 += ry; }
        }
        #pragma unroll
        for (int off = 1; off < 16; off <<= 1) {
            deg += __shfl_xor(deg, off);
            s0  += __shfl_xor(s0, off);
            s1  += __shfl_xor(s1, off);
            s2  += __shfl_xor(s2, off);
        }
        if (part == 0) {
            float dg = fmaxf(deg, 1.f);
            loopS[d * 3 + 0] = s0 / dg;
            loopS[d * 3 + 1] = s1 / dg;
            loopS[d * 3 + 2] = s2 / dg;
        }
    }
    if (tid == 0) {
        float nv = 0.f;
        for (int m = 0; m < 64; m++) nv += vmS[m] > 0.5f ? 1.f : 0.f;
        nvS = fmaxf(nv, 1.f);
    }

    {
        f32x4 acc[4];
        #pragma unroll
        for (int mt = 0; mt < 4; mt++) acc[mt] = (f32x4){0.f, 0.f, 0.f, 0.f};
        for (int ks = 0; ks < 8; ks++) {
            const unsigned short* fb = &BswAll[((size_t)(ks * 16 + nt) * 64 + lane) * 16];
            bf16x8 bhi = *(const bf16x8*)&fb[0];
            bf16x8 blo = *(const bf16x8*)&fb[8];
            #pragma unroll
            for (int mt = 0; mt < 4; mt++) {
                int ao = (mt * 16 + ln15) * XP + ks * 32 + q * 8;
                bf16x8 ahi = *(const bf16x8*)&xH[ao];
                bf16x8 alo = *(const bf16x8*)&xL[ao];
                acc[mt] = __builtin_amdgcn_mfma_f32_16x16x32_bf16(ahi, bhi, acc[mt], 0, 0, 0);
                acc[mt] = __builtin_amdgcn_mfma_f32_16x16x32_bf16(alo, bhi, acc[mt], 0, 0, 0);
                acc[mt] = __builtin_amdgcn_mfma_f32_16x16x32_bf16(ahi, blo, acc[mt], 0, 0, 0);
            }
        }
        __syncthreads();
        int c = nt * 16 + ln15;
        float bv = inb[c];
        #pragma unroll
        for (int mt = 0; mt < 4; mt++) {
            #pragma unroll
            for (int r = 0; r < 4; r++) {
                int m = mt * 16 + q * 4 + r;
                float v = (acc[mt][r] + bv) * (vmS[m] > 0.5f ? 1.f : 0.f);
                unsigned short hi = f2bf(v);
                xH[m * XP + c] = hi;
                xL[m * XP + c] = f2bf(v - bf2f(hi));
            }
        }
    }
    __syncthreads();

    for (int l = 0; l < 3; l++) {
        const unsigned short* BswL = BswAll + (size_t)(1 + l) * 16384 * 16;
        const float* biasl = gbias + (size_t)l * 256;
        const float* lnsl  = glns + (size_t)l * 256;
        const float* lnbl  = glnb + (size_t)l * 256;
        const float* wES   = wESall + l * 12;

        f32x4 acc[4];
        #pragma unroll
        for (int mt = 0; mt < 4; mt++) acc[mt] = (f32x4){0.f, 0.f, 0.f, 0.f};
        for (int ks = 0; ks < 8; ks++) {
            const unsigned short* fb = &BswL[((size_t)(ks * 16 + nt) * 64 + lane) * 16];
            bf16x8 bhi = *(const bf16x8*)&fb[0];
            bf16x8 blo = *(const bf16x8*)&fb[8];
            #pragma unroll
            for (int mt = 0; mt < 4; mt++) {
                int ao = (mt * 16 + ln15) * XP + ks * 32 + q * 8;
                bf16x8 ahi = *(const bf16x8*)&xH[ao];
                bf16x8 alo = *(const bf16x8*)&xL[ao];
                acc[mt] = __builtin_amdgcn_mfma_f32_16x16x32_bf16(ahi, bhi, acc[mt], 0, 0, 0);
                acc[mt] = __builtin_amdgcn_mfma_f32_16x16x32_bf16(alo, bhi, acc[mt], 0, 0, 0);
                acc[mt] = __builtin_amdgcn_mfma_f32_16x16x32_bf16(ahi, blo, acc[mt], 0, 0, 0);
            }
        }

        if (w >= 12) {
            int mm = w - 12;
            f32x4 aax = (f32x4){0.f, 0.f, 0.f, 0.f};
            const unsigned short* AuxL = auxB + (size_t)l * 8 * 64 * 16;
            for (int ks = 0; ks < 8; ks++) {
                const unsigned short* fb = &AuxL[((size_t)ks * 64 + lane) * 16];
                bf16x8 bhi = *(const bf16x8*)&fb[0];
                bf16x8 blo = *(const bf16x8*)&fb[8];
                int ao = (mm * 16 + ln15) * XP + ks * 32 + q * 8;
                bf16x8 ahi = *(const bf16x8*)&xH[ao];
                bf16x8 alo = *(const bf16x8*)&xL[ao];
                aax = __builtin_amdgcn_mfma_f32_16x16x32_bf16(ahi, bhi, aax, 0, 0, 0);
                aax = __builtin_amdgcn_mfma_f32_16x16x32_bf16(alo, bhi, aax, 0, 0, 0);
                aax = __builtin_amdgcn_mfma_f32_16x16x32_bf16(ahi, blo, aax, 0, 0, 0);
            }
            if (ln15 < 4) {
                #pragma unroll
                for (int r = 0; r < 4; r++) asrcS[ln15][mm * 16 + q * 4 + r] = aax[r];
            } else if (ln15 < 8) {
                #pragma unroll
                for (int r = 0; r < 4; r++) adstS[ln15 - 4][mm * 16 + q * 4 + r] = aax[r];
            }
        }

        f32x4 macc[4];
        #pragma unroll
        for (int ct = 0; ct < 4; ct++) {
            int c = eh * 64 + ct * 16 + ln15;
            float bv = biasl[c];
            #pragma unroll
            for (int r = 0; r < 4; r++) {
                int d2 = dq * 16 + q * 4 + r;
                int o = d2 * XP + c;
                macc[ct][r] = bf2f(xH[o]) + bf2f(xL[o]) + bv;
            }
        }
        __syncthreads();

        {
            int c = nt * 16 + ln15;
            #pragma unroll
            for (int mt = 0; mt < 4; mt++) {
                unsigned p0 = cvt2(acc[mt][0], acc[mt][1]);
                unsigned p1 = cvt2(acc[mt][2], acc[mt][3]);
                float h0 = ubf(p0 << 16), h1 = ubf(p0 & 0xFFFF0000u);
                float h2 = ubf(p1 << 16), h3 = ubf(p1 & 0xFFFF0000u);
                unsigned l0 = cvt2(acc[mt][0] - h0, acc[mt][1] - h1);
                unsigned l1 = cvt2(acc[mt][2] - h2, acc[mt][3] - h3);
                int s = mt * 16 + q * 4;
                *(unsigned*)&U[c * 136 + s]          = p0;
                *(unsigned*)&U[c * 136 + s + 2]      = p1;
                *(unsigned*)&U[c * 136 + 64 + s]     = l0;
                *(unsigned*)&U[c * 136 + 64 + s + 2] = l1;
            }
        }
        __syncthreads();

        {
            int d = dq * 16 + ln15;
            float pxd = pxS[d], pyd = pyS[d];
            bool vdv = vmS[d] > 0.5f;
            float adstv = adstS[eh][d];
            float lp0 = loopS[d * 3 + 0];
            float lp1 = loopS[d * 3 + 1];
            float lp2 = loopS[d * 3 + 2];
            float we0 = wES[eh], we1 = wES[4 + eh], we2 = wES[8 + eh];

            float lg[16];
            #pragma unroll
            for (int ks = 0; ks < 2; ks++) {
                int s0 = ks * 32 + q * 8;
                F8 PX, PY, VM, AS;
                PX.v2[0] = *(const float4*)&pxS[s0]; PX.v2[1] = *(const float4*)&pxS[s0 + 4];
                PY.v2[0] = *(const float4*)&pyS[s0]; PY.v2[1] = *(const float4*)&pyS[s0 + 4];
                VM.v2[0] = *(const float4*)&vmS[s0]; VM.v2[1] = *(const float4*)&vmS[s0 + 4];
                AS.v2[0] = *(const float4*)&asrcS[eh][s0];
                AS.v2[1] = *(const float4*)&asrcS[eh][s0 + 4];
                #pragma unroll
                for (int j = 0; j < 8; j++) {
                    int s = s0 + j;
                    float vsf = VM.f[j];
                    float rx = pxd - PX.f[j], ry = pyd - PY.f[j];
                    float dist = sqrtf(fmaxf(rx * rx + ry * ry, 1e-12f));
                    bool self = (s == d);
                    bool adj = vdv && (vsf > 0.5f) && (dist < 0.3f) && !self;
                    float e0 = adj ? dist : (self ? lp0 : 0.f);
                    float e1 = adj ? rx   : (self ? lp1 : 0.f);
                    float e2 = adj ? ry   : (self ? lp2 : 0.f);
                    bool fa = adj || (self && vdv);
                    float lv = AS.f[j] + adstv + e0 * we0 + e1 * we1 + e2 * we2;
                    lv = lv >= 0.f ? lv : 0.2f * lv;
                    lg[ks * 8 + j] = fa ? lv : -1e9f;
                }
            }

            float mx = lg[0];
            #pragma unroll
            for (int j = 1; j < 16; j++) mx = fmaxf(mx, lg[j]);
            mx = fmaxf(mx, __shfl_xor(mx, 16));
            mx = fmaxf(mx, __shfl_xor(mx, 32));
            float sm = 0.f;
            #pragma unroll
            for (int j = 0; j < 16; j++) { lg[j] = __expf(lg[j] - mx); sm += lg[j]; }
            sm += __shfl_xor(sm, 16);
            sm += __shfl_xor(sm, 32);
            float inv = 1.f / sm;

            bf16x8 ah[2], al[2];
            #pragma unroll
            for (int ks2 = 0; ks2 < 2; ks2++) {
                union { bf16x8 v; unsigned u[4]; } H, L;
                #pragma unroll
                for (int jj = 0; jj < 4; jj++) {
                    float a0 = lg[ks2 * 8 + jj * 2] * inv;
                    float a1 = lg[ks2 * 8 + jj * 2 + 1] * inv;
                    unsigned p = cvt2(a0, a1);
                    H.u[jj] = p;
                    float f0 = ubf(p << 16), f1 = ubf(p & 0xFFFF0000u);
                    L.u[jj] = cvt2(a0 - f0, a1 - f1);
                }
                ah[ks2] = H.v; al[ks2] = L.v;
            }

            #pragma unroll
            for (int ks2 = 0; ks2 < 2; ks2++) {
                #pragma unroll
                for (int ct = 0; ct < 4; ct++) {
                    const unsigned short* hb =
                        &U[(size_t)(eh * 64 + ct * 16 + ln15) * 136 + ks2 * 32 + q * 8];
                    bf16x8 bhi = *(const bf16x8*)&hb[0];
                    bf16x8 blo = *(const bf16x8*)&hb[64];
                    macc[ct] = __builtin_amdgcn_mfma_f32_16x16x32_bf16(ah[ks2], bhi, macc[ct], 0, 0, 0);
                    macc[ct] = __builtin_amdgcn_mfma_f32_16x16x32_bf16(al[ks2], bhi, macc[ct], 0, 0, 0);
                    macc[ct] = __builtin_amdgcn_mfma_f32_16x16x32_bf16(ah[ks2], blo, macc[ct], 0, 0, 0);
                }
            }
        }

        {
            float scv[4], bbv[4];
            #pragma unroll
            for (int ct = 0; ct < 4; ct++) {
                int c = eh * 64 + ct * 16 + ln15;
                scv[ct] = lnsl[c];
                bbv[ct] = lnbl[c];
            }
            float ps[4], ps2[4];
            #pragma unroll
            for (int r = 0; r < 4; r++) {
                float s = 0.f, s2 = 0.f;
                #pragma unroll
                for (int ct = 0; ct < 4; ct++) {
                    float v = macc[ct][r];
                    s += v; s2 += v * v;
                }
                ps[r] = s; ps2[r] = s2;
            }
            #pragma unroll
            for (int off = 1; off < 16; off <<= 1) {
                #pragma unroll
                for (int i = 0; i < 4; i++) {
                    ps[i]  += __shfl_xor(ps[i], off);
                    ps2[i] += __shfl_xor(ps2[i], off);
                }
            }
            if (ln15 == 0) {
                #pragma unroll
                for (int r = 0; r < 4; r++) {
                    int d2 = dq * 16 + q * 4 + r;
                    sumsS[d2][eh * 2 + 0] = ps[r];
                    sumsS[d2][eh * 2 + 1] = ps2[r];
                }
            }
            __syncthreads();
            if (tid < 64) {
                float S  = sumsS[tid][0] + sumsS[tid][2] + sumsS[tid][4] + sumsS[tid][6];
                float S2 = sumsS[tid][1] + sumsS[tid][3] + sumsS[tid][5] + sumsS[tid][7];
                float mu = S * (1.f / 256.f);
                float var = S2 * (1.f / 256.f) - mu * mu;
                mrsS[tid][0] = mu;
                mrsS[tid][1] = rsqrtf(var + 1e-5f);
            }
            __syncthreads();
            #pragma unroll
            for (int r = 0; r < 4; r++) {
                int d2 = dq * 16 + q * 4 + r;
                float mu = mrsS[d2][0], rs = mrsS[d2][1];
                #pragma unroll
                for (int ct = 0; ct < 4; ct++) {
                    float v = (macc[ct][r] - mu) * rs * scv[ct] + bbv[ct];
                    v = fmaxf(v, 0.f);
                    unsigned short hi = f2bf(v);
                    int o = d2 * XP + eh * 64 + ct * 16 + ln15;
                    xH[o] = hi;
                    xL[o] = f2bf(v - bf2f(hi));
                }
            }
        }
        __syncthreads();
    }

    if (tid < 256) {
        float s = 0.f;
        for (int m = 0; m < 64; m++) {
            float xv = bf2f(xH[m * XP + tid]) + bf2f(xL[m * XP + tid]);
            s += xv * (vmS[m] > 0.5f ? 1.f : 0.f);
        }
        framebuf[(size_t)bt * 256 + tid] = s / nvS;
    }
}

// ---------------------------------------------------------------------------
// Unified MFMA tile-GEMM for the transformer tail. Weights PRE-SWIZZLED
// (split bf16 hi/lo fragments via k_prep_tail) — inner loop is pure loads+MFMA.
#define TG_RELU 1
#define TG_RES  2
#define XPA 264
__global__ __launch_bounds__(256, 4) void k_tgemm(const float* __restrict__ A,
                                                  const float* __restrict__ lnS,
                                                  const float* __restrict__ lnB,
                                                  const unsigned short* __restrict__ Wsw,
                                                  const float* __restrict__ bias,
                                                  const float* __restrict__ pe,
                                                  float* __restrict__ out,
                                                  int K, int N, int ldo, int flags) {
    __shared__ __align__(16) unsigned short AH[64 * XPA];
    __shared__ __align__(16) unsigned short AL[64 * XPA];

    int tid = threadIdx.x;
    int lane = tid & 63, w = tid >> 6;
    int ln15 = lane & 15, q = lane >> 4;
    int Mbase = blockIdx.x * 64;
    int Nbase = blockIdx.y * 64;
    int r = tid >> 2, p = tid & 3;    // staging: row r, quarter p
    int nt16 = N >> 4;
    int ntile = (Nbase >> 4) + w;

    f32x4 acc[4];
    #pragma unroll
    for (int mt = 0; mt < 4; mt++) acc[mt] = (f32x4){0.f, 0.f, 0.f, 0.f};

    int nchunks = K >> 8;             // 1 (K=256) or 2 (K=512)
    for (int kc = 0; kc < nchunks; kc++) {
        {
            const float* arow = A + (size_t)(Mbase + r) * K + kc * 256 + p * 4;
            if (lnS && kc == 0) {
                float s = 0.f, s2 = 0.f;
                #pragma unroll
                for (int j = 0; j < 16; j++) {
                    float4 v = *(const float4*)&arow[j * 16];
                    s  += v.x + v.y + v.z + v.w;
                    s2 += v.x * v.x + v.y * v.y + v.z * v.z + v.w * v.w;
                }
                s  += __shfl_xor(s, 1);  s  += __shfl_xor(s, 2);
                s2 += __shfl_xor(s2, 1); s2 += __shfl_xor(s2, 2);
                float mu = s * (1.f / 256.f);
                float var = s2 * (1.f / 256.f) - mu * mu;
                float rstd = rsqrtf(var + 1e-5f);
                #pragma unroll
                for (int j = 0; j < 16; j++) {
                    int c = p * 4 + j * 16;
                    float4 v = *(const float4*)&arow[j * 16];
                    float4 ls = *(const float4*)&lnS[c];
                    float4 lb = *(const float4*)&lnB[c];
                    float4 z;
                    z.x = (v.x - mu) * rstd * ls.x + lb.x;
                    z.y = (v.y - mu) * rstd * ls.y + lb.y;
                    z.z = (v.z - mu) * rstd * ls.z + lb.z;
                    z.w = (v.w - mu) * rstd * ls.w + lb.w;
                    unsigned p0 = cvt2(z.x, z.y), p1 = cvt2(z.z, z.w);
                    float f0 = ubf(p0 << 16), f1 = ubf(p0 & 0xFFFF0000u);
                    float f2 = ubf(p1 << 16), f3 = ubf(p1 & 0xFFFF0000u);
                    unsigned l0 = cvt2(z.x - f0, z.y - f1);
                    unsigned l1 = cvt2(z.z - f2, z.w - f3);
                    *(unsigned*)&AH[r * XPA + c]     = p0;
                    *(unsigned*)&AH[r * XPA + c + 2] = p1;
                    *(unsigned*)&AL[r * XPA + c]     = l0;
                    *(unsigned*)&AL[r * XPA + c + 2] = l1;
                }
            } else {
                #pragma unroll
                for (int j = 0; j < 16; j++) {
                    int c = p * 4 + j * 16;
                    float4 v = *(const float4*)&arow[j * 16];
                    unsigned p0 = cvt2(v.x, v.y), p1 = cvt2(v.z, v.w);
                    float f0 = ubf(p0 << 16), f1 = ubf(p0 & 0xFFFF0000u);
                    float f2 = ubf(p1 << 16), f3 = ubf(p1 & 0xFFFF0000u);
                    unsigned l0 = cvt2(v.x - f0, v.y - f1);
                    unsigned l1 = cvt2(v.z - f2, v.w - f3);
                    *(unsigned*)&AH[r * XPA + c]     = p0;
                    *(unsigned*)&AH[r * XPA + c + 2] = p1;
                    *(unsigned*)&AL[r * XPA + c]     = l0;
                    *(unsigned*)&AL[r * XPA + c + 2] = l1;
                }
            }
        }
        __syncthreads();

        for (int ks = 0; ks < 8; ks++) {
            int ksg = kc * 8 + ks;
            const unsigned short* fb = &Wsw[((size_t)(ksg * nt16 + ntile) * 64 + lane) * 16];
            bf16x8 bhi = *(const bf16x8*)&fb[0];
            bf16x8 blo = *(const bf16x8*)&fb[8];
            #pragma unroll
            for (int mt = 0; mt < 4; mt++) {
                int ao = (mt * 16 + ln15) * XPA + ks * 32 + q * 8;
                bf16x8 ahi = *(const bf16x8*)&AH[ao];
                bf16x8 alo = *(const bf16x8*)&AL[ao];
                acc[mt] = __builtin_amdgcn_mfma_f32_16x16x32_bf16(ahi, bhi, acc[mt], 0, 0, 0);
                acc[mt] = __builtin_amdgcn_mfma_f32_16x16x32_bf16(alo, bhi, acc[mt], 0, 0, 0);
                acc[mt] = __builtin_amdgcn_mfma_f32_16x16x32_bf16(ahi, blo, acc[mt], 0, 0, 0);
            }
        }
        if (kc + 1 < nchunks) __syncthreads();
    }

    int n = Nbase + w * 16 + ln15;
    float bv = bias[n];
    #pragma unroll
    for (int mt = 0; mt < 4; mt++) {
        #pragma unroll
        for (int rr = 0; rr < 4; rr++) {
            int row = Mbase + mt * 16 + q * 4 + rr;
            float v = acc[mt][rr] + bv;
            if (pe) v += pe[(row & 31) * 256 + n];
            size_t oidx = (size_t)row * ldo + n;
            if (flags & TG_RES) v += out[oidx];
            if (flags & TG_RELU) v = fmaxf(v, 0.f);
            out[oidx] = v;
        }
    }
}

// ---------------------------------------------------------------------------
__global__ __launch_bounds__(64) void k_attn(const float* __restrict__ qkvbuf,
                                             float* __restrict__ obuf) {
    int blk = blockIdx.x;
    int b = blk >> 3, h = blk & 7;
    int tid = threadIdx.x;
    __shared__ float Ks[32 * 32], Vs[32 * 32];
    for (int idx = tid; idx < 1024; idx += 64) {
        int tk = idx >> 5, c = idx & 31;
        size_t qbase = ((size_t)(b * 32 + tk)) * 768 + h * 32 + c;
        Ks[idx] = qkvbuf[qbase + 256];
        Vs[idx] = qkvbuf[qbase + 512];
    }
    __syncthreads();
    if (tid < 32) {
        int tq = tid;
        float qv[32];
        size_t qb0 = ((size_t)(b * 32 + tq)) * 768 + h * 32;
        #pragma unroll
        for (int c = 0; c < 32; c++) qv[c] = qkvbuf[qb0 + c];
        float scr[32];
        float mx = -1e30f;
        #pragma unroll
        for (int tk = 0; tk < 32; tk++) {
            float dd = 0.f;
            #pragma unroll
            for (int c = 0; c < 32; c++) dd = fmaf(qv[c], Ks[tk * 32 + c], dd);
            dd *= 0.17677669529663687f;
            scr[tk] = dd;
            mx = fmaxf(mx, dd);
        }
        float sm = 0.f;
        #pragma unroll
        for (int tk = 0; tk < 32; tk++) { scr[tk] = __expf(scr[tk] - mx); sm += scr[tk]; }
        float inv = 1.f / sm;
        float o[32];
        #pragma unroll
        for (int c = 0; c < 32; c++) o[c] = 0.f;
        #pragma unroll
        for (int tk = 0; tk < 32; tk++) {
            float a = scr[tk] * inv;
            #pragma unroll
            for (int c = 0; c < 32; c++) o[c] = fmaf(a, Vs[tk * 32 + c], o[c]);
        }
        size_t ob = ((size_t)(b * 32 + tq)) * 256 + h * 32;
        #pragma unroll
        for (int c = 0; c < 32; c++) obuf[ob + c] = o[c];
    }
}

// ---------------------------------------------------------------------------
__global__ __launch_bounds__(256) void k_pool_out(const float* __restrict__ ybuf,
                                                  const float* __restrict__ pW,
                                                  const float* __restrict__ pb,
                                                  const float* __restrict__ oW,
                                                  const float* __restrict__ ob,
                                                  const float* __restrict__ lns,
                                                  const float* __restrict__ lnb,
                                                  float* __restrict__ dout) {
    int b = blockIdx.x, tid = threadIdx.x;
    __shared__ float redP[256];
    __shared__ float wS[32];
    __shared__ float pS[256];
    __shared__ float red[8];
    int tq = tid >> 3, part = tid & 7;
    float partial = 0.f;
    {
        const float* yrow = ybuf + ((size_t)(b * 32 + tq)) * 256 + part * 32;
        const float* pwp = pW + part * 32;
        #pragma unroll
        for (int j = 0; j < 32; j += 4) {
            float4 yv = *(const float4*)&yrow[j];
            float4 wv = *(const float4*)&pwp[j];
            partial += dot4(yv, wv);
        }
    }
    redP[tid] = partial;
    __syncthreads();
    if (tid < 32) {
        float s = pb[0];
        for (int p = 0; p < 8; p++) s += redP[tid * 8 + p];
        float mx = s;
        #pragma unroll
        for (int off = 16; off; off >>= 1) mx = fmaxf(mx, __shfl_xor(mx, off));
        float e = __expf(s - mx);
        float sm = e;
        #pragma unroll
        for (int off = 16; off; off >>= 1) sm += __shfl_xor(sm, off);
        wS[tid] = e / sm;
    }
    __syncthreads();
    float p = 0.f;
    for (int t = 0; t < 32; t++) p += ybuf[((size_t)(b * 32 + t)) * 256 + tid] * wS[t];
    pS[tid] = p;
    __syncthreads();
    float accs[2];
    for (int r = 0; r < 2; r++) {
        int j = r * 256 + tid;
        float acc = ob[j];
        const float* wrow = oW + (size_t)j * 256;
        for (int g = 0; g < 256; g += 4) {
            float4 pv = *(const float4*)&pS[g];
            float4 wv = *(const float4*)&wrow[g];
            acc += dot4(pv, wv);
        }
        accs[r] = acc;
    }
    float s = accs[0] + accs[1];
    float s2 = accs[0] * accs[0] + accs[1] * accs[1];
    #pragma unroll
    for (int off = 32; off; off >>= 1) {
        s += __shfl_xor(s, off);
        s2 += __shfl_xor(s2, off);
    }
    int wid = threadIdx.x >> 6;
    int lane = threadIdx.x & 63;
    if (lane == 0) { red[wid] = s; red[4 + wid] = s2; }
    __syncthreads();
    s = red[0] + red[1] + red[2] + red[3];
    s2 = red[4] + red[5] + red[6] + red[7];
    float mu = s * (1.f / 512.f);
    float var = s2 * (1.f / 512.f) - mu * mu;
    float rstd = rsqrtf(var + 1e-5f);
    dout[b * 512 + tid]       = fmaxf((accs[0] - mu) * rstd * lns[tid] + lnb[tid], 0.f);
    dout[b * 512 + tid + 256] = fmaxf((accs[1] - mu) * rstd * lns[tid + 256] + lnb[tid + 256], 0.f);
}

// ---------------------------------------------------------------------------
extern "C" void kernel_launch(void* const* d_in, const int* in_sizes, int n_in,
                              void* d_out, int out_size, void* d_ws, size_t ws_size,
                              hipStream_t stream) {
    const float* drone_feats = (const float*)d_in[0];
    const float* boxes       = (const float*)d_in[1];
    const float* drone_mask  = (const float*)d_in[2];
    const float* in_proj_W   = (const float*)d_in[3];
    const float* in_proj_b   = (const float*)d_in[4];
    const float* gat_lin_W   = (const float*)d_in[5];
    const float* gat_edge_W  = (const float*)d_in[6];
    const float* gat_att_src = (const float*)d_in[7];
    const float* gat_att_dst = (const float*)d_in[8];
    const float* gat_att_edge= (const float*)d_in[9];
    const float* gat_bias    = (const float*)d_in[10];
    const float* gat_ln_s    = (const float*)d_in[11];
    const float* gat_ln_b    = (const float*)d_in[12];
    const float* temp_W      = (const float*)d_in[13];
    const float* temp_b      = (const float*)d_in[14];
    const float* pos_emb     = (const float*)d_in[15];
    const float* qkv_W       = (const float*)d_in[16];
    const float* qkv_b       = (const float*)d_in[17];
    const float* attn_out_W  = (const float*)d_in[18];
    const float* attn_out_b  = (const float*)d_in[19];
    const float* ln1_s       = (const float*)d_in[20];
    const float* ln1_b       = (const float*)d_in[21];
    const float* ln2_s       = (const float*)d_in[22];
    const float* ln2_b       = (const float*)d_in[23];
    const float* ff1_W       = (const float*)d_in[24];
    const float* ff1_b       = (const float*)d_in[25];
    const float* ff2_W       = (const float*)d_in[26];
    const float* ff2_b       = (const float*)d_in[27];
    const float* pool_W      = (const float*)d_in[28];
    const float* pool_b      = (const float*)d_in[29];
    const float* out_W       = (const float*)d_in[30];
    const float* out_b       = (const float*)d_in[31];
    const float* out_ln_s    = (const float*)d_in[32];
    const float* out_ln_b    = (const float*)d_in[33];
    float* out = (float*)d_out;

    float* ws = (float*)d_ws;
    unsigned short* Bsw    = (unsigned short*)ws;                 // 4*16384*16 ush = 2 MB
    unsigned short* BswAux = Bsw + (size_t)4 * 16384 * 16;        // 3*8*64*16 ush = 24576
    unsigned short* Wsw    = BswAux + (size_t)3 * 8 * 64 * 16;    // 139264*16 ush = 4.25 MB
    size_t ushort_total = (size_t)4 * 16384 * 16 + 3 * 8 * 64 * 16 + (size_t)139264 * 16;
    size_t off = (ushort_total + 1) / 2;                          // floats
    float* framebuf = ws + off; off += (size_t)BT * 256;
    float* ybuf   = ws + off; off += (size_t)BT * 256;
    float* qkvbuf = ws + off; off += (size_t)BT * 768;
    float* obuf   = ws + off; off += (size_t)BT * 256;
    float* fbuf   = ws + off; off += (size_t)BT * 512;

    // Wsw fragment offsets (in ushorts = frag*16)
    const size_t W_TEMP = 0;
    const size_t W_QKV0 = (size_t)8192 * 16,   W_QKV1 = (size_t)32768 * 16;
    const size_t W_AO0  = (size_t)57344 * 16,  W_AO1  = (size_t)65536 * 16;
    const size_t W_FF10 = (size_t)73728 * 16,  W_FF11 = (size_t)90112 * 16;
    const size_t W_FF20 = (size_t)106496 * 16, W_FF21 = (size_t)122880 * 16;

    k_prep<<<dim3(256), dim3(256), 0, stream>>>(in_proj_W, gat_lin_W, Bsw);
    k_prep_aux<<<dim3(24), dim3(64), 0, stream>>>(gat_lin_W, gat_att_src, gat_att_dst, BswAux);
    k_prep_tail<<<dim3(2176), dim3(64), 0, stream>>>(temp_W, qkv_W, attn_out_W, ff1_W, ff2_W, Wsw);
    k_gnn<<<dim3(BT), dim3(1024), 0, stream>>>(drone_feats, boxes, drone_mask, Bsw, BswAux,
        in_proj_b, gat_edge_W, gat_att_edge,
        gat_bias, gat_ln_s, gat_ln_b, framebuf);
    // temp proj + pos_emb: ybuf = framebuf @ temp_W^T + temp_b + pe
    k_tgemm<<<dim3(BT / 64, 4), dim3(256), 0, stream>>>(framebuf, nullptr, nullptr,
        Wsw + W_TEMP, temp_b, pos_emb, ybuf, 256, 256, 256, 0);
    for (int l = 0; l < 2; l++) {
        // qkv = LN1(y) @ qkv_W^T + qkv_b
        k_tgemm<<<dim3(BT / 64, 12), dim3(256), 0, stream>>>(ybuf,
            ln1_s + l * 256, ln1_b + l * 256,
            Wsw + (l ? W_QKV1 : W_QKV0), qkv_b + l * 768, nullptr,
            qkvbuf, 256, 768, 768, 0);
        k_attn<<<dim3(512), dim3(64), 0, stream>>>(qkvbuf, obuf);
        // y += o @ ao_W^T + ao_b
        k_tgemm<<<dim3(BT / 64, 4), dim3(256), 0, stream>>>(obuf, nullptr, nullptr,
            Wsw + (l ? W_AO1 : W_AO0), attn_out_b + l * 256, nullptr,
            ybuf, 256, 256, 256, TG_RES);
        // f = relu(LN2(y) @ ff1_W^T + ff1_b)
        k_tgemm<<<dim3(BT / 64, 8), dim3(256), 0, stream>>>(ybuf,
            ln2_s + l * 256, ln2_b + l * 256,
            Wsw + (l ? W_FF11 : W_FF10), ff1_b + l * 512, nullptr,
            fbuf, 256, 512, 512, TG_RELU);
        // y += f @ ff2_W^T + ff2_b
        k_tgemm<<<dim3(BT / 64, 4), dim3(256), 0, stream>>>(fbuf, nullptr, nullptr,
            Wsw + (l ? W_FF21 : W_FF20), ff2_b + l * 256, nullptr,
            ybuf, 512, 256, 256, TG_RES);
    }
    k_pool_out<<<dim3(64), dim3(256), 0, stream>>>(ybuf, pool_W, pool_b, out_W, out_b,
                                                   out_ln_s, out_ln_b, out);
}